// Round 1
// baseline (82.811 us; speedup 1.0000x reference)
//
#include <hip/hip_runtime.h>

#define NPTS 8192
#define DIM  32
#define TILE 128
#define TPB  256
#define NT   (NPTS / TILE)          /* 64 tiles per dim */
#define NBLK (NT * (NT + 1) / 2)    /* 2080 upper-tri blocks */

// codon index (dict order of CODON_TABLE) -> biosynthetic family id, -1 = stop.
// Families: 0 glutamate(E,Q,P,R), 1 aspartate(D,N,T,I,M,K), 2 serine(S,G,C),
// 3 pyruvate(A,V,L), 4 aromatic(F,Y,W), 5 histidine(H). K -> aspartate (overwrite order).
__device__ const int FID[64] = {
    4,4,3,3, 3,3,3,3, 1,1,1,1, 3,3,3,3,   // UUx CUx AUx GUx
    2,2,2,2, 0,0,0,0, 1,1,1,1, 3,3,3,3,   // UCx CCx ACx GCx
    4,4,-1,-1, 5,5,0,0, 1,1,1,1, 1,1,0,0, // UAx CAx AAx GAx
    2,2,-1,4, 0,0,0,0, 2,2,0,0, 2,2,2,2   // UGx CGx AGx GGx
};

// Per-point squared norm + family id + family histogram (for analytic counts).
__global__ void prep_kernel(const float* __restrict__ x, const int* __restrict__ idx,
                            float* __restrict__ sq, int* __restrict__ fid,
                            int* __restrict__ cnts) {
    __shared__ int c[8];
    int tid = threadIdx.x;
    if (tid < 8) c[tid] = 0;
    __syncthreads();
    int gid = blockIdx.x * blockDim.x + tid;
    const float4* p = (const float4*)(x + (size_t)gid * DIM);
    float s = 0.f;
#pragma unroll
    for (int v = 0; v < 8; ++v) {
        float4 f = p[v];
        s += f.x * f.x + f.y * f.y + f.z * f.z + f.w * f.w;
    }
    sq[gid] = s;
    int f = FID[idx[gid] & 63];
    fid[gid] = f;
    atomicAdd(&c[f < 0 ? 6 : f], 1);
    __syncthreads();
    if (tid < 7) atomicAdd(&cnts[tid], c[tid]);
}

// One 128x128 pair tile per block, upper-triangle blocks only, weight x2.
// 8x8 register micro-tile per thread; k-major LDS tiles (K=32 fits fully).
__global__ __launch_bounds__(TPB) void pair_kernel(const float* __restrict__ x,
                                                   const float* __restrict__ sq,
                                                   const int* __restrict__ fid,
                                                   double* __restrict__ sums) {
    __shared__ float As[DIM][TILE];
    __shared__ float Bs[DIM][TILE];
    __shared__ float sqA[TILE], sqB[TILE];
    __shared__ int   fA[TILE],  fB[TILE];
    __shared__ double red[4][2];

    // linear block id -> upper-tri (I, J), J >= I. Offset(I) = I*NT - I*(I-1)/2
    int b = blockIdx.x;
    int I = (int)((2 * NT + 1 - sqrtf((float)((2 * NT + 1) * (2 * NT + 1) - 8 * b))) * 0.5f);
    if (I < 0) I = 0;
    if (I > NT - 1) I = NT - 1;
    while ((I + 1) * NT - (I + 1) * I / 2 <= b) ++I;
    while (I * NT - I * (I - 1) / 2 > b) --I;
    int J = I + (b - (I * NT - I * (I - 1) / 2));
    int I0 = I * TILE, J0 = J * TILE;

    int tid = threadIdx.x;
    {   // stage both tiles, transposing [pt][k] -> [k][pt]. Write conflicts 2-way (free).
        int pnt = tid >> 1, h = tid & 1;
        const float4* srcA = (const float4*)(x + (size_t)(I0 + pnt) * DIM + h * 16);
        const float4* srcB = (const float4*)(x + (size_t)(J0 + pnt) * DIM + h * 16);
#pragma unroll
        for (int v = 0; v < 4; ++v) {
            float4 fa = srcA[v];
            float4 fb = srcB[v];
            int kb = h * 16 + v * 4;
            As[kb + 0][pnt] = fa.x; As[kb + 1][pnt] = fa.y;
            As[kb + 2][pnt] = fa.z; As[kb + 3][pnt] = fa.w;
            Bs[kb + 0][pnt] = fb.x; Bs[kb + 1][pnt] = fb.y;
            Bs[kb + 2][pnt] = fb.z; Bs[kb + 3][pnt] = fb.w;
        }
    }
    if (tid < TILE) { sqA[tid] = sq[I0 + tid]; fA[tid] = fid[I0 + tid]; }
    else { int t = tid - TILE; sqB[t] = sq[J0 + t]; fB[t] = fid[J0 + t]; }
    __syncthreads();

    int ti = tid & 15, tj = tid >> 4;
    int i0 = ti * 8, j0 = tj * 8;

    float acc[8][8];
#pragma unroll
    for (int ii = 0; ii < 8; ++ii)
#pragma unroll
        for (int jj = 0; jj < 8; ++jj) acc[ii][jj] = 0.f;

#pragma unroll
    for (int k = 0; k < DIM; ++k) {
        float4 a0 = *(const float4*)&As[k][i0];
        float4 a1 = *(const float4*)&As[k][i0 + 4];
        float4 b0 = *(const float4*)&Bs[k][j0];
        float4 b1 = *(const float4*)&Bs[k][j0 + 4];
        float a[8]  = {a0.x, a0.y, a0.z, a0.w, a1.x, a1.y, a1.z, a1.w};
        float bb[8] = {b0.x, b0.y, b0.z, b0.w, b1.x, b1.y, b1.z, b1.w};
#pragma unroll
        for (int ii = 0; ii < 8; ++ii)
#pragma unroll
            for (int jj = 0; jj < 8; ++jj)
                acc[ii][jj] = fmaf(a[ii], bb[jj], acc[ii][jj]);
    }

    float sqa[8], sqb[8];
    int fa[8], fb[8];
#pragma unroll
    for (int u = 0; u < 8; ++u) {
        sqa[u] = sqA[i0 + u]; sqb[u] = sqB[j0 + u];
        fa[u]  = fA[i0 + u];  fb[u]  = fB[j0 + u];
    }

    bool diagblk = (I == J);
    float s_all = 0.f, s_same = 0.f;
#pragma unroll
    for (int ii = 0; ii < 8; ++ii) {
#pragma unroll
        for (int jj = 0; jj < 8; ++jj) {
            float sqd = sqa[ii] + sqb[jj] - 2.f * acc[ii][jj];
            float dst = sqrtf(fmaxf(sqd, 0.f));  // sqrt(0)=0 covers the where()
            if (diagblk && (i0 + ii) >= (j0 + jj)) dst = 0.f; // strict upper on diag
            s_all += dst;
            if (fa[ii] == fb[jj] && fa[ii] >= 0) s_same += dst;
        }
    }
    s_all *= 2.f;   // symmetry weight
    s_same *= 2.f;

#pragma unroll
    for (int off = 32; off >= 1; off >>= 1) {
        s_all  += __shfl_xor(s_all, off);
        s_same += __shfl_xor(s_same, off);
    }
    int wv = tid >> 6;
    if ((tid & 63) == 0) { red[wv][0] = (double)s_all; red[wv][1] = (double)s_same; }
    __syncthreads();
    if (tid == 0) {
        double ta = red[0][0] + red[1][0] + red[2][0] + red[3][0];
        double ts = red[0][1] + red[1][1] + red[2][1] + red[3][1];
        atomicAdd(&sums[0], ta);
        atomicAdd(&sums[1], ts);
    }
}

__global__ void final_kernel(const double* __restrict__ sums,
                             const int* __restrict__ cnts,
                             float* __restrict__ out) {
    double csame = 0.0;
#pragma unroll
    for (int f = 0; f < 6; ++f) csame += (double)cnts[f] * (double)cnts[f];
    double cdiff = (double)NPTS * (double)NPTS - csame;
    double s_all = sums[0], s_same = sums[1];
    double same_mean = s_same / (csame + 1e-10);
    double diff_mean = (s_all - s_same) / (cdiff + 1e-10);
    double loss = same_mean - 0.5 * diff_mean + 1.0;
    out[0] = (float)(loss > 0.0 ? loss : 0.0);
}

extern "C" void kernel_launch(void* const* d_in, const int* in_sizes, int n_in,
                              void* d_out, int out_size, void* d_ws, size_t ws_size,
                              hipStream_t stream) {
    const float* x  = (const float*)d_in[0];   // (16,512,32) f32 -> 8192x32
    const int* idx  = (const int*)d_in[1];     // (16,512) int
    float* out      = (float*)d_out;

    // ws: [0..16) double sums[2]; [16..48) int cnts[8]; [64..) sq[8192] f32; then fid[8192] i32
    double* sums = (double*)d_ws;
    int* cnts    = (int*)((char*)d_ws + 16);
    float* sq    = (float*)((char*)d_ws + 64);
    int* fid     = (int*)((char*)d_ws + 64 + NPTS * sizeof(float));

    hipMemsetAsync(d_ws, 0, 64, stream);
    prep_kernel<<<NPTS / TPB, TPB, 0, stream>>>(x, idx, sq, fid, cnts);
    pair_kernel<<<NBLK, TPB, 0, stream>>>(x, sq, fid, sums);
    final_kernel<<<1, 1, 0, stream>>>(sums, cnts, out);
}